// Round 11
// baseline (135.564 us; speedup 1.0000x reference)
//
#include <hip/hip_runtime.h>
#include <hip/hip_bf16.h>
#include <math.h>

typedef __attribute__((ext_vector_type(8))) short bf16x8;
typedef __attribute__((ext_vector_type(4))) float f32x4;

#define MFMA16(a,b,c) __builtin_amdgcn_mfma_f32_16x16x32_bf16((a),(b),(c),0,0,0)

union U8 { uint4 u; bf16x8 v; };

__device__ __forceinline__ unsigned int pack2(float a, float b){
  __hip_bfloat162 h = __float22bfloat162_rn(float2{a, b});
  union { __hip_bfloat162 h; unsigned int u; } v; v.h = h;
  return v.u;
}
__device__ __forceinline__ float bflo(unsigned int u){ union{unsigned int i; float f;} v; v.i = u << 16; return v.f; }
__device__ __forceinline__ float bfhi(unsigned int u){ union{unsigned int i; float f;} v; v.i = u & 0xffff0000u; return v.f; }

// gelu(tanh approx) = x * sigmoid(2*0.79788456*(x+0.044715x^3))
__device__ __forceinline__ float gelu_tanh_f(float x){
  float x2 = x * x;
  float z  = x * fmaf(x2, -0.10294823f, -2.3022082f);
  float e  = exp2f(z);
  return x * __builtin_amdgcn_rcpf(1.0f + e);
}
__device__ __forceinline__ float gelu_erf_f(float x){
  return 0.5f * x * (1.0f + erff(x * 0.70710678118654752f));
}

// ---------------- prep: weights -> bf16, [out][in] layout ----------------
// wt layout (elements): W1T[128][256] @0, W2T[128][128] @32768, W3T[128][128] @49152,
//                       WinT[512][128] @65536, WoutT[128][512] @131072  (total 196608)
__global__ void k_prep(const float* __restrict__ W1, const float* __restrict__ W2,
                       const float* __restrict__ W3, const float* __restrict__ Win,
                       const float* __restrict__ Wout, unsigned short* __restrict__ wt)
{
  int t = blockIdx.x * 256 + threadIdx.x;
  if (t >= 196608) return;
  float v;
  if (t < 32768){            int o = t >> 8,        i = t & 255;         v = W1[i*128 + o]; }
  else if (t < 49152){       int l = t - 32768, o = l >> 7, i = l & 127; v = W2[i*128 + o]; }
  else if (t < 65536){       int l = t - 49152, o = l >> 7, i = l & 127; v = W3[i*128 + o]; }
  else if (t < 131072){      int l = t - 65536, o = l >> 7, i = l & 127; v = Win[i*512 + o]; }
  else {                     int l = t - 131072, o = l >> 9, i = l & 511; v = Wout[i*128 + o]; }
  union { float f; unsigned int u; } w; w.f = v;
  unsigned int r = w.u + 0x7fffu + ((w.u >> 16) & 1u);
  wt[t] = (unsigned short)(r >> 16);
}

// ---------------- hVp = hV @ W1a^T + b1  (per node, bf16 out) ----------------
__global__ __launch_bounds__(256)
void k_hvp(const float* __restrict__ hV, const unsigned short* __restrict__ wt,
           const float* __restrict__ b1, unsigned short* __restrict__ hVpb)
{
  __shared__ char sH[32*256];   // 32 nodes x 128 bf16 (swizzled)
  const int tid = threadIdx.x;
  const int wv  = tid >> 6;
  const int ln  = tid & 63;
  const int l15 = ln & 15;
  const int l4  = ln >> 4;
  const int swz = (l15 & 7) << 4;
  const unsigned short* W1T = wt;   // [128][256], cols 0..127 = h_V part
  const int nb = blockIdx.x * 32;

#pragma unroll
  for (int it = 0; it < 2; ++it){
    int cid = tid + it*256;       // 32 rows x 16 chunks
    int r = cid >> 4, cb = cid & 15;
    const float* src = hV + (size_t)(nb + r)*128 + cb*8;
    float4 a0 = *(const float4*)(src);
    float4 a1 = *(const float4*)(src + 4);
    uint4 w;
    w.x = pack2(a0.x, a0.y); w.y = pack2(a0.z, a0.w);
    w.z = pack2(a1.x, a1.y); w.w = pack2(a1.z, a1.w);
    *(uint4*)(&sH[r*256 + ((cb*16) ^ ((r&7)<<4))]) = w;
  }
  __syncthreads();

  f32x4 acc[2][2];
#pragma unroll
  for (int m = 0; m < 2; ++m){ acc[m][0] = f32x4{0.f,0.f,0.f,0.f}; acc[m][1] = f32x4{0.f,0.f,0.f,0.f}; }
#pragma unroll
  for (int ks = 0; ks < 4; ++ks){
    bf16x8 x0 = *(const bf16x8*)(&sH[(l15)*256      + ((ks*64 + l4*16) ^ swz)]);
    bf16x8 x1 = *(const bf16x8*)(&sH[(16 + l15)*256 + ((ks*64 + l4*16) ^ swz)]);
#pragma unroll
    for (int m = 0; m < 2; ++m){
      int orow = (wv*2 + m)*16 + l15;
      bf16x8 wf = *(const bf16x8*)(W1T + orow*256 + ks*32 + l4*8);
      acc[m][0] = MFMA16(wf, x0, acc[m][0]);
      acc[m][1] = MFMA16(wf, x1, acc[m][1]);
    }
  }
#pragma unroll
  for (int m = 0; m < 2; ++m){
    int och0 = (wv*2 + m)*16 + l4*4;
    float q0 = b1[och0], q1 = b1[och0+1], q2 = b1[och0+2], q3 = b1[och0+3];
#pragma unroll
    for (int nt = 0; nt < 2; ++nt){
      int node = nb + nt*16 + l15;
      uint2 p;
      p.x = pack2(acc[m][nt][0] + q0, acc[m][nt][1] + q1);
      p.y = pack2(acc[m][nt][2] + q2, acc[m][nt][3] + q3);
      *(uint2*)(hVpb + (size_t)node*128 + och0) = p;
    }
  }
}

// ---------------- message MLP: barrier-free, one wave = one node ----------------
// 256-thr blocks (4 waves), W1e in LDS (32 KB), W2 fragments straight from L1/L2.
// Each wave computes ALL 128 channels for its node's 48 rows (3 chunks of 16).
__global__ __launch_bounds__(256, 2)
void k_msg(const float* __restrict__ hE, const int* __restrict__ Eidx,
           const float* __restrict__ maskA, const unsigned short* __restrict__ wt,
           const unsigned short* __restrict__ hVpb, const float* __restrict__ b2,
           float* __restrict__ S, float* __restrict__ msums)
{
  __shared__ char sW1[32768];   // W1e^T [128 out][128 k] bf16, row-swizzled

  const int tid = threadIdx.x;
  const int wv  = tid >> 6;
  const int ln  = tid & 63;
  const int l15 = ln & 15;
  const int l4  = ln >> 4;
  const int wswz = (l15 & 7) << 4;            // weight-row swizzle (row&7 == l15&7)

  const unsigned short* W2G = wt + 32768;     // [128][128] bf16, stays in L1/L2

  // stage W1e once (2048 uint4 chunks)
#pragma unroll
  for (int it = 0; it < 8; ++it){
    int f = tid + it*256;
    int r = f >> 4, cb = f & 15;
    uint4 w1c = *(const uint4*)(wt + r*256 + 128 + cb*8);          // W1 h_E half
    *(uint4*)(&sW1[r*256 + ((cb*16) ^ ((r&7)<<4))]) = w1c;
  }
  __syncthreads();

  const int node = blockIdx.x * 4 + wv;
  const size_t bb = ((size_t)(node >> 11)) << 11;

  // per-chunk edge indices / masks (rows chunk*16 + l15)
  int eidx0, eidx1, eidx2; float emk0, emk1, emk2;
  {
    const int*   ip = Eidx  + node*48 + l15;
    const float* mp = maskA + node*48 + l15;
    eidx0 = ip[0]; eidx1 = ip[16]; eidx2 = ip[32];
    emk0  = mp[0]; emk1  = mp[16]; emk2  = mp[32];
  }

  f32x4 ssum[8];
#pragma unroll
  for (int t = 0; t < 8; ++t) ssum[t] = f32x4{0.f,0.f,0.f,0.f};

#pragma unroll
  for (int c = 0; c < 3; ++c){
    const int   cidx = (c == 0) ? eidx0 : (c == 1) ? eidx1 : eidx2;
    const float cmk  = (c == 0) ? emk0  : (c == 1) ? emk1  : emk2;

    // ---- X: 16 rows x 128 k, straight from global (fp32) into B-fragments
    const float* xp = hE + (size_t)(node*48 + c*16 + l15)*128 + l4*8;
    float4 xr[8];
#pragma unroll
    for (int ks = 0; ks < 4; ++ks){
      xr[2*ks]   = *(const float4*)(xp + ks*32);
      xr[2*ks+1] = *(const float4*)(xp + ks*32 + 4);
    }
    // hVp gather for this chunk's rows (consumed after GEMM1)
    uint2 hp[8];
    {
      const unsigned short* hb = hVpb + (bb + (size_t)cidx)*128 + l4*4;
#pragma unroll
      for (int t = 0; t < 8; ++t) hp[t] = *(const uint2*)(hb + 16*t);
    }
    bf16x8 xf[4];
#pragma unroll
    for (int ks = 0; ks < 4; ++ks){
      U8 xu;
      xu.u.x = pack2(xr[2*ks].x,   xr[2*ks].y);
      xu.u.y = pack2(xr[2*ks].z,   xr[2*ks].w);
      xu.u.z = pack2(xr[2*ks+1].x, xr[2*ks+1].y);
      xu.u.w = pack2(xr[2*ks+1].z, xr[2*ks+1].w);
      xf[ks] = xu.v;
    }

    // ---- GEMM1: all 8 output tiles, K=128 (weights from LDS)
    f32x4 a1[8];
#pragma unroll
    for (int t = 0; t < 8; ++t) a1[t] = f32x4{0.f,0.f,0.f,0.f};
#pragma unroll
    for (int ks = 0; ks < 4; ++ks){
#pragma unroll
      for (int t = 0; t < 8; ++t){
        bf16x8 wf = *(const bf16x8*)(&sW1[(16*t + l15)*256 + ((ks*64 + l4*16) ^ wswz)]);
        a1[t] = MFMA16(wf, xf[ks], a1[t]);
      }
    }

    // ---- E1: m1 = gelu(a1 + hVp[idx]) ; pack to q[t][rp] (bf16 pairs, C layout)
    unsigned int q[8][2];
#pragma unroll
    for (int t = 0; t < 8; ++t){
      float g0 = gelu_tanh_f(a1[t][0] + bflo(hp[t].x));
      float g1 = gelu_tanh_f(a1[t][1] + bfhi(hp[t].x));
      float g2 = gelu_tanh_f(a1[t][2] + bflo(hp[t].y));
      float g3 = gelu_tanh_f(a1[t][3] + bfhi(hp[t].y));
      q[t][0] = pack2(g0, g1);
      q[t][1] = pack2(g2, g3);
    }

    // ---- GEMM2 with in-register exchange: C-layout -> B-frag per ks2 window.
    // dest (l4, p) needs q[2*ks2 + l4/2][p&1] from lane l15 + 16*(2*(l4&1)+(p>>1))
    f32x4 a2[8];
#pragma unroll
    for (int t = 0; t < 8; ++t) a2[t] = f32x4{0.f,0.f,0.f,0.f};
    const bool lo = (l4 < 2);
    const int srcbase = l15 + 32*(l4 & 1);
#pragma unroll
    for (int ks2 = 0; ks2 < 4; ++ks2){
      unsigned int xw[4];
#pragma unroll
      for (int p = 0; p < 4; ++p){
        int src = srcbase + 16*(p >> 1);
        unsigned int va = (unsigned int)__shfl((int)q[2*ks2][p & 1],     src, 64);
        unsigned int vb = (unsigned int)__shfl((int)q[2*ks2 + 1][p & 1], src, 64);
        xw[p] = lo ? va : vb;
      }
      U8 xb; xb.u.x = xw[0]; xb.u.y = xw[1]; xb.u.z = xw[2]; xb.u.w = xw[3];
#pragma unroll
      for (int t = 0; t < 8; ++t){
        bf16x8 wf = *(const bf16x8*)(W2G + (16*t + l15)*128 + ks2*32 + l4*8);
        a2[t] = MFMA16(wf, xb.v, a2[t]);
      }
    }

    // ---- E2: ssum += mask * gelu(a2 + b2)
#pragma unroll
    for (int t = 0; t < 8; ++t){
      const float4 bq = *(const float4*)(b2 + 16*t + l4*4);
      ssum[t][0] += cmk * gelu_tanh_f(a2[t][0] + bq.x);
      ssum[t][1] += cmk * gelu_tanh_f(a2[t][1] + bq.y);
      ssum[t][2] += cmk * gelu_tanh_f(a2[t][2] + bq.z);
      ssum[t][3] += cmk * gelu_tanh_f(a2[t][3] + bq.w);
    }
  }

  // ---- reduce over the 16 rows (l15 lanes) and write S
#pragma unroll
  for (int t = 0; t < 8; ++t){
#pragma unroll
    for (int r = 0; r < 4; ++r){
#pragma unroll
      for (int off = 1; off < 16; off <<= 1)
        ssum[t][r] += __shfl_xor(ssum[t][r], off, 16);
    }
  }
  if (l15 == 0){
#pragma unroll
    for (int t = 0; t < 8; ++t){
      float4 o;
      o.x = ssum[t][0] * (1.0f/30.0f);
      o.y = ssum[t][1] * (1.0f/30.0f);
      o.z = ssum[t][2] * (1.0f/30.0f);
      o.w = ssum[t][3] * (1.0f/30.0f);
      *(float4*)(S + (size_t)node*128 + 16*t + l4*4) = o;
    }
  }
  {
    float qs = emk0 + emk1 + emk2;
#pragma unroll
    for (int off = 1; off < 16; off <<= 1) qs += __shfl_xor(qs, off, 16);
    if (ln == 0) msums[node] = qs * (1.0f/30.0f);
  }
}

// ---------------- FFN (+ commuted W3 matvec front) ----------------
__global__ __launch_bounds__(256, 2)
void k_ffn(const float* __restrict__ hV, const float* __restrict__ S,
           const float* __restrict__ msums, const float* __restrict__ maskV,
           const unsigned short* __restrict__ wt,
           const float* __restrict__ b3, const float* __restrict__ bin,
           const float* __restrict__ bout, float* __restrict__ out)
{
  __shared__ char  sS[32*256];    // 32 nodes x 128 bf16 (swizzled) : S
  __shared__ char  sH[32*256];    // 32 nodes x 128 bf16 (swizzled) : h
  __shared__ float sHf[32*132];   // fp32 h (padded rows, for residual)
  __shared__ char  sF[32*1024];   // 32 nodes x 512 bf16 (swizzled) : ff

  const int tid = threadIdx.x;
  const int wv  = tid >> 6;
  const int ln  = tid & 63;
  const int l15 = ln & 15;
  const int l4  = ln >> 4;
  const int swz = (l15 & 7) << 4;
  const unsigned short* W3T   = wt + 49152;    // [128][128]
  const unsigned short* WinT  = wt + 65536;    // [512][128]
  const unsigned short* WoutT = wt + 131072;   // [128][512]
  const int nb = blockIdx.x * 32;              // flat node base

  // stage S tile
#pragma unroll
  for (int it = 0; it < 2; ++it){
    int cid = tid + it*256;          // 32 rows x 16 chunks
    int r = cid >> 4, cb = cid & 15;
    const float* src = S + (size_t)(nb + r)*128 + cb*8;
    float4 a0 = *(const float4*)(src);
    float4 a1 = *(const float4*)(src + 4);
    uint4 w;
    w.x = pack2(a0.x, a0.y); w.y = pack2(a0.z, a0.w);
    w.z = pack2(a1.x, a1.y); w.w = pack2(a1.z, a1.w);
    *(uint4*)(&sS[r*256 + ((cb*16) ^ ((r&7)<<4))]) = w;
  }
  __syncthreads();

  // G0: dh^T[128][32] = W3T x S^T, K=128 ; h = hV + dh + msum*b3
  {
    f32x4 acc[2][2];
#pragma unroll
    for (int m = 0; m < 2; ++m){ acc[m][0] = f32x4{0.f,0.f,0.f,0.f}; acc[m][1] = f32x4{0.f,0.f,0.f,0.f}; }
#pragma unroll
    for (int ks = 0; ks < 4; ++ks){
      bf16x8 x0 = *(const bf16x8*)(&sS[(l15)*256      + ((ks*64 + l4*16) ^ swz)]);
      bf16x8 x1 = *(const bf16x8*)(&sS[(16 + l15)*256 + ((ks*64 + l4*16) ^ swz)]);
#pragma unroll
      for (int m = 0; m < 2; ++m){
        int cr = (wv*2 + m)*16 + l15;
        bf16x8 wf = *(const bf16x8*)(W3T + cr*128 + ks*32 + l4*8);
        acc[m][0] = MFMA16(wf, x0, acc[m][0]);
        acc[m][1] = MFMA16(wf, x1, acc[m][1]);
      }
    }
#pragma unroll
    for (int m = 0; m < 2; ++m){
      int ch0 = (wv*2 + m)*16 + l4*4;
      const float4 b3q = *(const float4*)(b3 + ch0);
#pragma unroll
      for (int nt = 0; nt < 2; ++nt){
        int row  = nt*16 + l15;
        int node = nb + row;
        float ms = msums[node];
        const float4 hv = *(const float4*)(hV + (size_t)node*128 + ch0);
        float h0 = hv.x + acc[m][nt][0] + ms*b3q.x;
        float h1 = hv.y + acc[m][nt][1] + ms*b3q.y;
        float h2 = hv.z + acc[m][nt][2] + ms*b3q.z;
        float h3 = hv.w + acc[m][nt][3] + ms*b3q.w;
        float4 hf; hf.x = h0; hf.y = h1; hf.z = h2; hf.w = h3;
        *(float4*)(&sHf[row*132 + ch0]) = hf;
        uint2 p; p.x = pack2(h0, h1); p.y = pack2(h2, h3);
        *(uint2*)(&sH[row*256 + ((ch0*2) ^ ((row&7)<<4))]) = p;
      }
    }
  }
  __syncthreads();

  // G1: ff^T[512][32] = WinT x h^T, K=128 — wave owns 8 f-tiles
  f32x4 accA[8][2];
#pragma unroll
  for (int m8 = 0; m8 < 8; ++m8){ accA[m8][0] = f32x4{0.f,0.f,0.f,0.f}; accA[m8][1] = f32x4{0.f,0.f,0.f,0.f}; }
#pragma unroll
  for (int ks = 0; ks < 4; ++ks){
    bf16x8 x0 = *(const bf16x8*)(&sH[(l15)*256      + ((ks*64 + l4*16) ^ swz)]);
    bf16x8 x1 = *(const bf16x8*)(&sH[(16 + l15)*256 + ((ks*64 + l4*16) ^ swz)]);
#pragma unroll
    for (int m8 = 0; m8 < 8; ++m8){
      int fr = (wv*8 + m8)*16 + l15;
      bf16x8 wf = *(const bf16x8*)(WinT + fr*128 + ks*32 + l4*8);
      accA[m8][0] = MFMA16(wf, x0, accA[m8][0]);
      accA[m8][1] = MFMA16(wf, x1, accA[m8][1]);
    }
  }
#pragma unroll
  for (int m8 = 0; m8 < 8; ++m8){
    int f0 = (wv*8 + m8)*16 + l4*4;
    float q0 = bin[f0], q1 = bin[f0+1], q2 = bin[f0+2], q3 = bin[f0+3];
#pragma unroll
    for (int nt = 0; nt < 2; ++nt){
      int row = nt*16 + l15;
      float g0 = gelu_erf_f(accA[m8][nt][0] + q0);
      float g1 = gelu_erf_f(accA[m8][nt][1] + q1);
      float g2 = gelu_erf_f(accA[m8][nt][2] + q2);
      float g3 = gelu_erf_f(accA[m8][nt][3] + q3);
      uint2 p; p.x = pack2(g0, g1); p.y = pack2(g2, g3);
      *(uint2*)(&sF[row*1024 + ((f0*2) ^ swz)]) = p;
    }
  }
  __syncthreads();

  // G2: dh2^T[128][32] = WoutT x ff^T, K=512 — wave owns 2 ch-tiles
  f32x4 accB[2][2];
#pragma unroll
  for (int m = 0; m < 2; ++m){ accB[m][0] = f32x4{0.f,0.f,0.f,0.f}; accB[m][1] = f32x4{0.f,0.f,0.f,0.f}; }
#pragma unroll
  for (int ks = 0; ks < 16; ++ks){
    bf16x8 x0 = *(const bf16x8*)(&sF[(l15)*1024      + ((ks*64 + l4*16) ^ swz)]);
    bf16x8 x1 = *(const bf16x8*)(&sF[(16 + l15)*1024 + ((ks*64 + l4*16) ^ swz)]);
#pragma unroll
    for (int m = 0; m < 2; ++m){
      int cr = (wv*2 + m)*16 + l15;
      bf16x8 wf = *(const bf16x8*)(WoutT + cr*512 + ks*32 + l4*8);
      accB[m][0] = MFMA16(wf, x0, accB[m][0]);
      accB[m][1] = MFMA16(wf, x1, accB[m][1]);
    }
  }
#pragma unroll
  for (int m = 0; m < 2; ++m){
    int ch0 = (wv*2 + m)*16 + l4*4;
    float q0 = bout[ch0], q1 = bout[ch0+1], q2 = bout[ch0+2], q3 = bout[ch0+3];
#pragma unroll
    for (int nt = 0; nt < 2; ++nt){
      int row  = nt*16 + l15;
      int node = nb + row;
      float mv = maskV[node];
      const float4 hf = *(const float4*)(&sHf[row*132 + ch0]);
      float4 o;
      o.x = mv * (hf.x + accB[m][nt][0] + q0);
      o.y = mv * (hf.y + accB[m][nt][1] + q1);
      o.z = mv * (hf.z + accB[m][nt][2] + q2);
      o.w = mv * (hf.w + accB[m][nt][3] + q3);
      *(float4*)(out + (size_t)node*128 + ch0) = o;
    }
  }
}

extern "C" void kernel_launch(void* const* d_in, const int* in_sizes, int n_in,
                              void* d_out, int out_size, void* d_ws, size_t ws_size,
                              hipStream_t stream)
{
  const float* hV    = (const float*)d_in[0];
  const float* hE    = (const float*)d_in[1];
  const int*   Eidx  = (const int*)  d_in[2];
  const float* maskV = (const float*)d_in[3];
  const float* maskA = (const float*)d_in[4];
  const float* W1w = (const float*)d_in[5];
  const float* W1b = (const float*)d_in[6];
  const float* W2w = (const float*)d_in[7];
  const float* W2b = (const float*)d_in[8];
  const float* W3w = (const float*)d_in[9];
  const float* W3b = (const float*)d_in[10];
  const float* Winw  = (const float*)d_in[11];
  const float* Winb  = (const float*)d_in[12];
  const float* Woutw = (const float*)d_in[13];
  const float* Woutb = (const float*)d_in[14];
  float* out = (float*)d_out;

  unsigned short* wt   = (unsigned short*)d_ws;                        // 384 KB bf16 weights
  unsigned short* hVpb = (unsigned short*)((char*)d_ws + (1u << 19));  // 2 MB bf16 hVp
  float* Sbuf  = (float*)((char*)d_ws + (1u << 19) + (1u << 21));      // 4 MB fp32 S
  float* msums = (float*)((char*)d_ws + (1u << 19) + (1u << 21) + (1u << 22)); // 32 KB

  k_prep<<<dim3(768),  dim3(256), 0, stream>>>(W1w, W2w, W3w, Winw, Woutw, wt);
  k_hvp <<<dim3(256),  dim3(256), 0, stream>>>(hV, wt, W1b, hVpb);
  k_msg <<<dim3(2048), dim3(256), 0, stream>>>(hE, Eidx, maskA, wt, hVpb, W2b, Sbuf, msums);
  k_ffn <<<dim3(256),  dim3(256), 0, stream>>>(hV, Sbuf, msums, maskV, wt, W3b, Winb, Woutb, out);
}

// Round 12
// 116.868 us; speedup vs baseline: 1.1600x; 1.1600x over previous
//
#include <hip/hip_runtime.h>
#include <hip/hip_bf16.h>
#include <math.h>

typedef __attribute__((ext_vector_type(8))) short bf16x8;
typedef __attribute__((ext_vector_type(4))) float f32x4;

#define MFMA16(a,b,c) __builtin_amdgcn_mfma_f32_16x16x32_bf16((a),(b),(c),0,0,0)

__device__ __forceinline__ unsigned int pack2(float a, float b){
  __hip_bfloat162 h = __float22bfloat162_rn(float2{a, b});
  union { __hip_bfloat162 h; unsigned int u; } v; v.h = h;
  return v.u;
}
__device__ __forceinline__ float bflo(unsigned int u){ union{unsigned int i; float f;} v; v.i = u << 16; return v.f; }
__device__ __forceinline__ float bfhi(unsigned int u){ union{unsigned int i; float f;} v; v.i = u & 0xffff0000u; return v.f; }

// gelu(tanh approx) = x * sigmoid(2*0.79788456*(x+0.044715x^3))
__device__ __forceinline__ float gelu_tanh_f(float x){
  float x2 = x * x;
  float z  = x * fmaf(x2, -0.10294823f, -2.3022082f);
  float e  = exp2f(z);
  return x * __builtin_amdgcn_rcpf(1.0f + e);
}
__device__ __forceinline__ float gelu_erf_f(float x){
  return 0.5f * x * (1.0f + erff(x * 0.70710678118654752f));
}

// ---------------- prep: weights -> bf16, [out][in] layout ----------------
// wt layout (elements): W1T[128][256] @0, W2T[128][128] @32768, W3T[128][128] @49152,
//                       WinT[512][128] @65536, WoutT[128][512] @131072  (total 196608)
__global__ void k_prep(const float* __restrict__ W1, const float* __restrict__ W2,
                       const float* __restrict__ W3, const float* __restrict__ Win,
                       const float* __restrict__ Wout, unsigned short* __restrict__ wt)
{
  int t = blockIdx.x * 256 + threadIdx.x;
  if (t >= 196608) return;
  float v;
  if (t < 32768){            int o = t >> 8,        i = t & 255;         v = W1[i*128 + o]; }
  else if (t < 49152){       int l = t - 32768, o = l >> 7, i = l & 127; v = W2[i*128 + o]; }
  else if (t < 65536){       int l = t - 49152, o = l >> 7, i = l & 127; v = W3[i*128 + o]; }
  else if (t < 131072){      int l = t - 65536, o = l >> 7, i = l & 127; v = Win[i*512 + o]; }
  else {                     int l = t - 131072, o = l >> 9, i = l & 511; v = Wout[i*128 + o]; }
  union { float f; unsigned int u; } w; w.f = v;
  unsigned int r = w.u + 0x7fffu + ((w.u >> 16) & 1u);
  wt[t] = (unsigned short)(r >> 16);
}

// ---------------- hVp = hV @ W1a^T + b1  (per node, bf16 out) ----------------
__global__ __launch_bounds__(256)
void k_hvp(const float* __restrict__ hV, const unsigned short* __restrict__ wt,
           const float* __restrict__ b1, unsigned short* __restrict__ hVpb)
{
  __shared__ char sH[32*256];   // 32 nodes x 128 bf16 (swizzled)
  const int tid = threadIdx.x;
  const int wv  = tid >> 6;
  const int ln  = tid & 63;
  const int l15 = ln & 15;
  const int l4  = ln >> 4;
  const int swz = (l15 & 7) << 4;
  const unsigned short* W1T = wt;   // [128][256], cols 0..127 = h_V part
  const int nb = blockIdx.x * 32;

#pragma unroll
  for (int it = 0; it < 2; ++it){
    int cid = tid + it*256;       // 32 rows x 16 chunks
    int r = cid >> 4, cb = cid & 15;
    const float* src = hV + (size_t)(nb + r)*128 + cb*8;
    float4 a0 = *(const float4*)(src);
    float4 a1 = *(const float4*)(src + 4);
    uint4 w;
    w.x = pack2(a0.x, a0.y); w.y = pack2(a0.z, a0.w);
    w.z = pack2(a1.x, a1.y); w.w = pack2(a1.z, a1.w);
    *(uint4*)(&sH[r*256 + ((cb*16) ^ ((r&7)<<4))]) = w;
  }
  __syncthreads();

  f32x4 acc[2][2];
#pragma unroll
  for (int m = 0; m < 2; ++m){ acc[m][0] = f32x4{0.f,0.f,0.f,0.f}; acc[m][1] = f32x4{0.f,0.f,0.f,0.f}; }
#pragma unroll
  for (int ks = 0; ks < 4; ++ks){
    bf16x8 x0 = *(const bf16x8*)(&sH[(l15)*256      + ((ks*64 + l4*16) ^ swz)]);
    bf16x8 x1 = *(const bf16x8*)(&sH[(16 + l15)*256 + ((ks*64 + l4*16) ^ swz)]);
#pragma unroll
    for (int m = 0; m < 2; ++m){
      int orow = (wv*2 + m)*16 + l15;
      bf16x8 wf = *(const bf16x8*)(W1T + orow*256 + ks*32 + l4*8);
      acc[m][0] = MFMA16(wf, x0, acc[m][0]);
      acc[m][1] = MFMA16(wf, x1, acc[m][1]);
    }
  }
#pragma unroll
  for (int m = 0; m < 2; ++m){
    int och0 = (wv*2 + m)*16 + l4*4;
    float q0 = b1[och0], q1 = b1[och0+1], q2 = b1[och0+2], q3 = b1[och0+3];
#pragma unroll
    for (int nt = 0; nt < 2; ++nt){
      int node = nb + nt*16 + l15;
      uint2 p;
      p.x = pack2(acc[m][nt][0] + q0, acc[m][nt][1] + q1);
      p.y = pack2(acc[m][nt][2] + q2, acc[m][nt][3] + q3);
      *(uint2*)(hVpb + (size_t)node*128 + och0) = p;
    }
  }
}

// ---------------- message MLP (GEMM1+GEMM2) + masked K-sum -> S ----------------
// R6 champion structure, but node loop FULLY ROLLED (one body copy ~4KB) to fit I$.
// 8 waves x 16 channels, 48-row (1-node) tiles, 2 barriers/node, bf16 hVp gathers.
#define NPB 4
__global__ __launch_bounds__(512, 4)
void k_msg(const float* __restrict__ hE, const int* __restrict__ Eidx,
           const float* __restrict__ maskA, const unsigned short* __restrict__ wt,
           const unsigned short* __restrict__ hVpb, const float* __restrict__ b2,
           float* __restrict__ S, float* __restrict__ msums)
{
  __shared__ char sE[2][12288];  // h_E tile (48x128 bf16, swizzled), double-buffered
  __shared__ char sM[12288];     // m1

  const int tid = threadIdx.x;
  const int wv  = tid >> 6;        // 0..7 -> 16-channel m-tile
  const int ln  = tid & 63;
  const int l15 = ln & 15;
  const int l4  = ln >> 4;
  const int swz = (l15 & 7) << 4;

  const unsigned short* W1T = wt;            // [128][256]; h_E part at col 128
  const unsigned short* W2T = wt + 32768;    // [128][128]

  // loop-invariant weight fragments (32 VGPR)
  bf16x8 w1f[4], w2f[4];
  {
    int orow = wv*16 + l15;
#pragma unroll
    for (int ks = 0; ks < 4; ++ks){
      w1f[ks] = *(const bf16x8*)(W1T + orow*256 + 128 + ks*32 + l4*8);
      w2f[ks] = *(const bf16x8*)(W2T + orow*128 + ks*32 + l4*8);
    }
  }
  const int och0 = wv*16 + l4*4;
  const float4 b2q = *(const float4*)(b2 + och0);

  // loop-invariant LDS lane offsets
  int xoff[4];
#pragma unroll
  for (int ks = 0; ks < 4; ++ks) xoff[ks] = l15*256 + ((ks*64 + l4*16) ^ swz);
  const int woff  = l15*256 + ((och0*2) ^ swz);
  const int soff0 = (tid>>5)*256 + (((tid&31)*8) ^ (((tid>>5)&7)<<4));

  const int node0 = blockIdx.x * NPB;

  // one-node-ahead prefetch registers
  float4 e0, e1, e2;
  int pidx0, pidx1, pidx2; float pmk0, pmk1, pmk2;
  {
    const float4* ef = (const float4*)(hE + (size_t)node0 * 6144);
    e0 = ef[tid]; e1 = ef[tid + 512]; e2 = ef[tid + 1024];
    const int* ip = Eidx + node0*48 + l15;
    pidx0 = ip[0]; pidx1 = ip[16]; pidx2 = ip[32];
    const float* mp = maskA + node0*48 + l15;
    pmk0 = mp[0]; pmk1 = mp[16]; pmk2 = mp[32];
  }

#pragma unroll 1
  for (int i = 0; i < NPB; ++i){
    const int node = node0 + i;
    const size_t bb = ((size_t)(node >> 11)) << 11;
    char* sEc = sE[i & 1];

    // consume prefetched idx/mask; issue hVp gathers (bf16, consumed after GEMM1)
    const float mk0 = pmk0, mk1 = pmk1, mk2 = pmk2;
    uint2 hp0, hp1, hp2;
    {
      const unsigned short* base = hVpb + bb*128 + och0;
      hp0 = *(const uint2*)(base + (size_t)pidx0 * 128);
      hp1 = *(const uint2*)(base + (size_t)pidx1 * 128);
      hp2 = *(const uint2*)(base + (size_t)pidx2 * 128);
    }
    // S1: stage h_E tile from prefetched regs
    {
      uint2 p;
      p.x = pack2(e0.x, e0.y); p.y = pack2(e0.z, e0.w);
      *(uint2*)(sEc + soff0) = p;
      p.x = pack2(e1.x, e1.y); p.y = pack2(e1.z, e1.w);
      *(uint2*)(sEc + soff0 + 4096) = p;
      p.x = pack2(e2.x, e2.y); p.y = pack2(e2.z, e2.w);
      *(uint2*)(sEc + soff0 + 8192) = p;
    }
    // prefetch next node
    if (i + 1 < NPB){
      const float4* ef = (const float4*)(hE + (size_t)(node + 1) * 6144);
      e0 = ef[tid]; e1 = ef[tid + 512]; e2 = ef[tid + 1024];
      const int* ip = Eidx + (node+1)*48 + l15;
      pidx0 = ip[0]; pidx1 = ip[16]; pidx2 = ip[32];
      const float* mp = maskA + (node+1)*48 + l15;
      pmk0 = mp[0]; pmk1 = mp[16]; pmk2 = mp[32];
    }
    __syncthreads();                                   // B1: sEc staged

    // ---- GEMM1: K=128 (h_E x W1e)
    f32x4 a0 = f32x4{0.f,0.f,0.f,0.f}, a1 = a0, a2 = a0;
#pragma unroll
    for (int ks = 0; ks < 4; ++ks){
      bf16x8 x0 = *(const bf16x8*)(sEc + xoff[ks]);
      bf16x8 x1 = *(const bf16x8*)(sEc + xoff[ks] + 4096);
      bf16x8 x2 = *(const bf16x8*)(sEc + xoff[ks] + 8192);
      a0 = MFMA16(w1f[ks], x0, a0);
      a1 = MFMA16(w1f[ks], x1, a1);
      a2 = MFMA16(w1f[ks], x2, a2);
    }
    // E1: + gathered hVp (has b1), gelu -> sM
    {
      uint2 p;
      p.x = pack2(gelu_tanh_f(a0[0] + bflo(hp0.x)), gelu_tanh_f(a0[1] + bfhi(hp0.x)));
      p.y = pack2(gelu_tanh_f(a0[2] + bflo(hp0.y)), gelu_tanh_f(a0[3] + bfhi(hp0.y)));
      *(uint2*)(sM + woff) = p;
      p.x = pack2(gelu_tanh_f(a1[0] + bflo(hp1.x)), gelu_tanh_f(a1[1] + bfhi(hp1.x)));
      p.y = pack2(gelu_tanh_f(a1[2] + bflo(hp1.y)), gelu_tanh_f(a1[3] + bfhi(hp1.y)));
      *(uint2*)(sM + woff + 4096) = p;
      p.x = pack2(gelu_tanh_f(a2[0] + bflo(hp2.x)), gelu_tanh_f(a2[1] + bfhi(hp2.x)));
      p.y = pack2(gelu_tanh_f(a2[2] + bflo(hp2.y)), gelu_tanh_f(a2[3] + bfhi(hp2.y)));
      *(uint2*)(sM + woff + 8192) = p;
    }
    __syncthreads();                                   // B2: sM ready

    // ---- GEMM2: K=128
    a0 = f32x4{0.f,0.f,0.f,0.f}; a1 = a0; a2 = a0;
#pragma unroll
    for (int ks = 0; ks < 4; ++ks){
      bf16x8 x0 = *(const bf16x8*)(sM + xoff[ks]);
      bf16x8 x1 = *(const bf16x8*)(sM + xoff[ks] + 4096);
      bf16x8 x2 = *(const bf16x8*)(sM + xoff[ks] + 8192);
      a0 = MFMA16(w2f[ks], x0, a0);
      a1 = MFMA16(w2f[ks], x1, a1);
      a2 = MFMA16(w2f[ks], x2, a2);
    }
    // E2: m2 = gelu(acc + b2); masked sum over 48 edges -> S[node][ch]/30
    {
      float s0, s1, s2, s3;
      s0  = mk0 * gelu_tanh_f(a0[0] + b2q.x);
      s1  = mk0 * gelu_tanh_f(a0[1] + b2q.y);
      s2  = mk0 * gelu_tanh_f(a0[2] + b2q.z);
      s3  = mk0 * gelu_tanh_f(a0[3] + b2q.w);
      s0 += mk1 * gelu_tanh_f(a1[0] + b2q.x);
      s1 += mk1 * gelu_tanh_f(a1[1] + b2q.y);
      s2 += mk1 * gelu_tanh_f(a1[2] + b2q.z);
      s3 += mk1 * gelu_tanh_f(a1[3] + b2q.w);
      s0 += mk2 * gelu_tanh_f(a2[0] + b2q.x);
      s1 += mk2 * gelu_tanh_f(a2[1] + b2q.y);
      s2 += mk2 * gelu_tanh_f(a2[2] + b2q.z);
      s3 += mk2 * gelu_tanh_f(a2[3] + b2q.w);
#pragma unroll
      for (int off = 1; off < 16; off <<= 1){
        s0 += __shfl_xor(s0, off, 16);
        s1 += __shfl_xor(s1, off, 16);
        s2 += __shfl_xor(s2, off, 16);
        s3 += __shfl_xor(s3, off, 16);
      }
      if (l15 == 0){
        float4 o;
        o.x = s0 * (1.0f/30.0f);
        o.y = s1 * (1.0f/30.0f);
        o.z = s2 * (1.0f/30.0f);
        o.w = s3 * (1.0f/30.0f);
        *(float4*)(S + (size_t)node*128 + och0) = o;
      }
      if (wv == 0){
        float q = mk0 + mk1 + mk2;
#pragma unroll
        for (int off = 1; off < 16; off <<= 1) q += __shfl_xor(q, off, 16);
        if (ln == 0) msums[node] = q * (1.0f/30.0f);
      }
    }
  }
}

// ---------------- FFN (+ commuted W3 matvec front) ----------------
__global__ __launch_bounds__(256, 2)
void k_ffn(const float* __restrict__ hV, const float* __restrict__ S,
           const float* __restrict__ msums, const float* __restrict__ maskV,
           const unsigned short* __restrict__ wt,
           const float* __restrict__ b3, const float* __restrict__ bin,
           const float* __restrict__ bout, float* __restrict__ out)
{
  __shared__ char  sS[32*256];    // 32 nodes x 128 bf16 (swizzled) : S
  __shared__ char  sH[32*256];    // 32 nodes x 128 bf16 (swizzled) : h
  __shared__ float sHf[32*132];   // fp32 h (padded rows, for residual)
  __shared__ char  sF[32*1024];   // 32 nodes x 512 bf16 (swizzled) : ff

  const int tid = threadIdx.x;
  const int wv  = tid >> 6;
  const int ln  = tid & 63;
  const int l15 = ln & 15;
  const int l4  = ln >> 4;
  const int swz = (l15 & 7) << 4;
  const unsigned short* W3T   = wt + 49152;    // [128][128]
  const unsigned short* WinT  = wt + 65536;    // [512][128]
  const unsigned short* WoutT = wt + 131072;   // [128][512]
  const int nb = blockIdx.x * 32;              // flat node base

  // stage S tile
#pragma unroll
  for (int it = 0; it < 2; ++it){
    int cid = tid + it*256;          // 32 rows x 16 chunks
    int r = cid >> 4, cb = cid & 15;
    const float* src = S + (size_t)(nb + r)*128 + cb*8;
    float4 a0 = *(const float4*)(src);
    float4 a1 = *(const float4*)(src + 4);
    uint4 w;
    w.x = pack2(a0.x, a0.y); w.y = pack2(a0.z, a0.w);
    w.z = pack2(a1.x, a1.y); w.w = pack2(a1.z, a1.w);
    *(uint4*)(&sS[r*256 + ((cb*16) ^ ((r&7)<<4))]) = w;
  }
  __syncthreads();

  // G0: dh^T[128][32] = W3T x S^T, K=128 ; h = hV + dh + msum*b3
  {
    f32x4 acc[2][2];
#pragma unroll
    for (int m = 0; m < 2; ++m){ acc[m][0] = f32x4{0.f,0.f,0.f,0.f}; acc[m][1] = f32x4{0.f,0.f,0.f,0.f}; }
#pragma unroll
    for (int ks = 0; ks < 4; ++ks){
      bf16x8 x0 = *(const bf16x8*)(&sS[(l15)*256      + ((ks*64 + l4*16) ^ swz)]);
      bf16x8 x1 = *(const bf16x8*)(&sS[(16 + l15)*256 + ((ks*64 + l4*16) ^ swz)]);
#pragma unroll
      for (int m = 0; m < 2; ++m){
        int cr = (wv*2 + m)*16 + l15;
        bf16x8 wf = *(const bf16x8*)(W3T + cr*128 + ks*32 + l4*8);
        acc[m][0] = MFMA16(wf, x0, acc[m][0]);
        acc[m][1] = MFMA16(wf, x1, acc[m][1]);
      }
    }
#pragma unroll
    for (int m = 0; m < 2; ++m){
      int ch0 = (wv*2 + m)*16 + l4*4;
      const float4 b3q = *(const float4*)(b3 + ch0);
#pragma unroll
      for (int nt = 0; nt < 2; ++nt){
        int row  = nt*16 + l15;
        int node = nb + row;
        float ms = msums[node];
        const float4 hv = *(const float4*)(hV + (size_t)node*128 + ch0);
        float h0 = hv.x + acc[m][nt][0] + ms*b3q.x;
        float h1 = hv.y + acc[m][nt][1] + ms*b3q.y;
        float h2 = hv.z + acc[m][nt][2] + ms*b3q.z;
        float h3 = hv.w + acc[m][nt][3] + ms*b3q.w;
        float4 hf; hf.x = h0; hf.y = h1; hf.z = h2; hf.w = h3;
        *(float4*)(&sHf[row*132 + ch0]) = hf;
        uint2 p; p.x = pack2(h0, h1); p.y = pack2(h2, h3);
        *(uint2*)(&sH[row*256 + ((ch0*2) ^ ((row&7)<<4))]) = p;
      }
    }
  }
  __syncthreads();

  // G1: ff^T[512][32] = WinT x h^T, K=128 — wave owns 8 f-tiles
  f32x4 accA[8][2];
#pragma unroll
  for (int m8 = 0; m8 < 8; ++m8){ accA[m8][0] = f32x4{0.f,0.f,0.f,0.f}; accA[m8][1] = f32x4{0.f,0.f,0.f,0.f}; }
#pragma unroll
  for (int ks = 0; ks < 4; ++ks){
    bf16x8 x0 = *(const bf16x8*)(&sH[(l15)*256      + ((ks*64 + l4*16) ^ swz)]);
    bf16x8 x1 = *(const bf16x8*)(&sH[(16 + l15)*256 + ((ks*64 + l4*16) ^ swz)]);
#pragma unroll
    for (int m8 = 0; m8 < 8; ++m8){
      int fr = (wv*8 + m8)*16 + l15;
      bf16x8 wf = *(const bf16x8*)(WinT + fr*128 + ks*32 + l4*8);
      accA[m8][0] = MFMA16(wf, x0, accA[m8][0]);
      accA[m8][1] = MFMA16(wf, x1, accA[m8][1]);
    }
  }
#pragma unroll
  for (int m8 = 0; m8 < 8; ++m8){
    int f0 = (wv*8 + m8)*16 + l4*4;
    float q0 = bin[f0], q1 = bin[f0+1], q2 = bin[f0+2], q3 = bin[f0+3];
#pragma unroll
    for (int nt = 0; nt < 2; ++nt){
      int row = nt*16 + l15;
      float g0 = gelu_erf_f(accA[m8][nt][0] + q0);
      float g1 = gelu_erf_f(accA[m8][nt][1] + q1);
      float g2 = gelu_erf_f(accA[m8][nt][2] + q2);
      float g3 = gelu_erf_f(accA[m8][nt][3] + q3);
      uint2 p; p.x = pack2(g0, g1); p.y = pack2(g2, g3);
      *(uint2*)(&sF[row*1024 + ((f0*2) ^ swz)]) = p;
    }
  }
  __syncthreads();

  // G2: dh2^T[128][32] = WoutT x ff^T, K=512 — wave owns 2 ch-tiles
  f32x4 accB[2][2];
#pragma unroll
  for (int m = 0; m < 2; ++m){ accB[m][0] = f32x4{0.f,0.f,0.f,0.f}; accB[m][1] = f32x4{0.f,0.f,0.f,0.f}; }
#pragma unroll
  for (int ks = 0; ks < 16; ++ks){
    bf16x8 x0 = *(const bf16x8*)(&sF[(l15)*1024      + ((ks*64 + l4*16) ^ swz)]);
    bf16x8 x1 = *(const bf16x8*)(&sF[(16 + l15)*1024 + ((ks*64 + l4*16) ^ swz)]);
#pragma unroll
    for (int m = 0; m < 2; ++m){
      int cr = (wv*2 + m)*16 + l15;
      bf16x8 wf = *(const bf16x8*)(WoutT + cr*512 + ks*32 + l4*8);
      accB[m][0] = MFMA16(wf, x0, accB[m][0]);
      accB[m][1] = MFMA16(wf, x1, accB[m][1]);
    }
  }
#pragma unroll
  for (int m = 0; m < 2; ++m){
    int ch0 = (wv*2 + m)*16 + l4*4;
    float q0 = bout[ch0], q1 = bout[ch0+1], q2 = bout[ch0+2], q3 = bout[ch0+3];
#pragma unroll
    for (int nt = 0; nt < 2; ++nt){
      int row  = nt*16 + l15;
      int node = nb + row;
      float mv = maskV[node];
      const float4 hf = *(const float4*)(&sHf[row*132 + ch0]);
      float4 o;
      o.x = mv * (hf.x + accB[m][nt][0] + q0);
      o.y = mv * (hf.y + accB[m][nt][1] + q1);
      o.z = mv * (hf.z + accB[m][nt][2] + q2);
      o.w = mv * (hf.w + accB[m][nt][3] + q3);
      *(float4*)(out + (size_t)node*128 + ch0) = o;
    }
  }
}

extern "C" void kernel_launch(void* const* d_in, const int* in_sizes, int n_in,
                              void* d_out, int out_size, void* d_ws, size_t ws_size,
                              hipStream_t stream)
{
  const float* hV    = (const float*)d_in[0];
  const float* hE    = (const float*)d_in[1];
  const int*   Eidx  = (const int*)  d_in[2];
  const float* maskV = (const float*)d_in[3];
  const float* maskA = (const float*)d_in[4];
  const float* W1w = (const float*)d_in[5];
  const float* W1b = (const float*)d_in[6];
  const float* W2w = (const float*)d_in[7];
  const float* W2b = (const float*)d_in[8];
  const float* W3w = (const float*)d_in[9];
  const float* W3b = (const float*)d_in[10];
  const float* Winw  = (const float*)d_in[11];
  const float* Winb  = (const float*)d_in[12];
  const float* Woutw = (const float*)d_in[13];
  const float* Woutb = (const float*)d_in[14];
  float* out = (float*)d_out;

  unsigned short* wt   = (unsigned short*)d_ws;                        // 384 KB bf16 weights
  unsigned short* hVpb = (unsigned short*)((char*)d_ws + (1u << 19));  // 2 MB bf16 hVp
  float* Sbuf  = (float*)((char*)d_ws + (1u << 19) + (1u << 21));      // 4 MB fp32 S
  float* msums = (float*)((char*)d_ws + (1u << 19) + (1u << 21) + (1u << 22)); // 32 KB

  k_prep<<<dim3(768),  dim3(256), 0, stream>>>(W1w, W2w, W3w, Winw, Woutw, wt);
  k_hvp <<<dim3(256),  dim3(256), 0, stream>>>(hV, wt, W1b, hVpb);
  k_msg <<<dim3(2048), dim3(512), 0, stream>>>(hE, Eidx, maskA, wt, hVpb, W2b, Sbuf, msums);
  k_ffn <<<dim3(256),  dim3(256), 0, stream>>>(hV, Sbuf, msums, maskV, wt, W3b, Winb, Woutb, out);
}

// Round 13
// 114.670 us; speedup vs baseline: 1.1822x; 1.0192x over previous
//
#include <hip/hip_runtime.h>
#include <hip/hip_bf16.h>
#include <math.h>

typedef __attribute__((ext_vector_type(8))) short bf16x8;
typedef __attribute__((ext_vector_type(4))) float f32x4;

#define MFMA16(a,b,c) __builtin_amdgcn_mfma_f32_16x16x32_bf16((a),(b),(c),0,0,0)

__device__ __forceinline__ unsigned int pack2(float a, float b){
  __hip_bfloat162 h = __float22bfloat162_rn(float2{a, b});
  union { __hip_bfloat162 h; unsigned int u; } v; v.h = h;
  return v.u;
}
__device__ __forceinline__ float bflo(unsigned int u){ union{unsigned int i; float f;} v; v.i = u << 16; return v.f; }
__device__ __forceinline__ float bfhi(unsigned int u){ union{unsigned int i; float f;} v; v.i = u & 0xffff0000u; return v.f; }

// message-MLP gelu: x*sigmoid(1.702x) = x*rcp(1+exp2(-2.4554x))  (3V+2T)
// max |delta| vs tanh-approx ~0.013/element; within absmax budget (see R13 notes)
__device__ __forceinline__ float gelu_fast_f(float x){
  float e = exp2f(x * -2.4554236f);
  return x * __builtin_amdgcn_rcpf(1.0f + e);
}
// exact-form tanh gelu kept for k_hvp-adjacent paths (unused in k_msg now)
__device__ __forceinline__ float gelu_erf_f(float x){
  return 0.5f * x * (1.0f + erff(x * 0.70710678118654752f));
}

// ---------------- prep: weights -> bf16, [out][in] layout ----------------
// wt layout (elements): W1T[128][256] @0, W2T[128][128] @32768, W3T[128][128] @49152,
//                       WinT[512][128] @65536, WoutT[128][512] @131072  (total 196608)
__global__ void k_prep(const float* __restrict__ W1, const float* __restrict__ W2,
                       const float* __restrict__ W3, const float* __restrict__ Win,
                       const float* __restrict__ Wout, unsigned short* __restrict__ wt)
{
  int t = blockIdx.x * 256 + threadIdx.x;
  if (t >= 196608) return;
  float v;
  if (t < 32768){            int o = t >> 8,        i = t & 255;         v = W1[i*128 + o]; }
  else if (t < 49152){       int l = t - 32768, o = l >> 7, i = l & 127; v = W2[i*128 + o]; }
  else if (t < 65536){       int l = t - 49152, o = l >> 7, i = l & 127; v = W3[i*128 + o]; }
  else if (t < 131072){      int l = t - 65536, o = l >> 7, i = l & 127; v = Win[i*512 + o]; }
  else {                     int l = t - 131072, o = l >> 9, i = l & 511; v = Wout[i*128 + o]; }
  union { float f; unsigned int u; } w; w.f = v;
  unsigned int r = w.u + 0x7fffu + ((w.u >> 16) & 1u);
  wt[t] = (unsigned short)(r >> 16);
}

// ---------------- hVp = hV @ W1a^T + b1  (per node, bf16 out) ----------------
__global__ __launch_bounds__(256)
void k_hvp(const float* __restrict__ hV, const unsigned short* __restrict__ wt,
           const float* __restrict__ b1, unsigned short* __restrict__ hVpb)
{
  __shared__ char sH[32*256];   // 32 nodes x 128 bf16 (swizzled)
  const int tid = threadIdx.x;
  const int wv  = tid >> 6;
  const int ln  = tid & 63;
  const int l15 = ln & 15;
  const int l4  = ln >> 4;
  const int swz = (l15 & 7) << 4;
  const unsigned short* W1T = wt;   // [128][256], cols 0..127 = h_V part
  const int nb = blockIdx.x * 32;

#pragma unroll
  for (int it = 0; it < 2; ++it){
    int cid = tid + it*256;       // 32 rows x 16 chunks
    int r = cid >> 4, cb = cid & 15;
    const float* src = hV + (size_t)(nb + r)*128 + cb*8;
    float4 a0 = *(const float4*)(src);
    float4 a1 = *(const float4*)(src + 4);
    uint4 w;
    w.x = pack2(a0.x, a0.y); w.y = pack2(a0.z, a0.w);
    w.z = pack2(a1.x, a1.y); w.w = pack2(a1.z, a1.w);
    *(uint4*)(&sH[r*256 + ((cb*16) ^ ((r&7)<<4))]) = w;
  }
  __syncthreads();

  f32x4 acc[2][2];
#pragma unroll
  for (int m = 0; m < 2; ++m){ acc[m][0] = f32x4{0.f,0.f,0.f,0.f}; acc[m][1] = f32x4{0.f,0.f,0.f,0.f}; }
#pragma unroll
  for (int ks = 0; ks < 4; ++ks){
    bf16x8 x0 = *(const bf16x8*)(&sH[(l15)*256      + ((ks*64 + l4*16) ^ swz)]);
    bf16x8 x1 = *(const bf16x8*)(&sH[(16 + l15)*256 + ((ks*64 + l4*16) ^ swz)]);
#pragma unroll
    for (int m = 0; m < 2; ++m){
      int orow = (wv*2 + m)*16 + l15;
      bf16x8 wf = *(const bf16x8*)(W1T + orow*256 + ks*32 + l4*8);
      acc[m][0] = MFMA16(wf, x0, acc[m][0]);
      acc[m][1] = MFMA16(wf, x1, acc[m][1]);
    }
  }
#pragma unroll
  for (int m = 0; m < 2; ++m){
    int och0 = (wv*2 + m)*16 + l4*4;
    float q0 = b1[och0], q1 = b1[och0+1], q2 = b1[och0+2], q3 = b1[och0+3];
#pragma unroll
    for (int nt = 0; nt < 2; ++nt){
      int node = nb + nt*16 + l15;
      uint2 p;
      p.x = pack2(acc[m][nt][0] + q0, acc[m][nt][1] + q1);
      p.y = pack2(acc[m][nt][2] + q2, acc[m][nt][3] + q3);
      *(uint2*)(hVpb + (size_t)node*128 + och0) = p;
    }
  }
}

// ---------------- message MLP (GEMM1+GEMM2) + masked K-sum -> S ----------------
// R12 champion structure; R13 = sigma-gelu + width-64 shfl (instruction-count cut).
#define NPB 4
__global__ __launch_bounds__(512, 4)
void k_msg(const float* __restrict__ hE, const int* __restrict__ Eidx,
           const float* __restrict__ maskA, const unsigned short* __restrict__ wt,
           const unsigned short* __restrict__ hVpb, const float* __restrict__ b2,
           float* __restrict__ S, float* __restrict__ msums)
{
  __shared__ char sE[2][12288];  // h_E tile (48x128 bf16, swizzled), double-buffered
  __shared__ char sM[12288];     // m1

  const int tid = threadIdx.x;
  const int wv  = tid >> 6;        // 0..7 -> 16-channel m-tile
  const int ln  = tid & 63;
  const int l15 = ln & 15;
  const int l4  = ln >> 4;
  const int swz = (l15 & 7) << 4;

  const unsigned short* W1T = wt;            // [128][256]; h_E part at col 128
  const unsigned short* W2T = wt + 32768;    // [128][128]

  // loop-invariant weight fragments (32 VGPR)
  bf16x8 w1f[4], w2f[4];
  {
    int orow = wv*16 + l15;
#pragma unroll
    for (int ks = 0; ks < 4; ++ks){
      w1f[ks] = *(const bf16x8*)(W1T + orow*256 + 128 + ks*32 + l4*8);
      w2f[ks] = *(const bf16x8*)(W2T + orow*128 + ks*32 + l4*8);
    }
  }
  const int och0 = wv*16 + l4*4;
  const float4 b2q = *(const float4*)(b2 + och0);

  // loop-invariant LDS lane offsets
  int xoff[4];
#pragma unroll
  for (int ks = 0; ks < 4; ++ks) xoff[ks] = l15*256 + ((ks*64 + l4*16) ^ swz);
  const int woff  = l15*256 + ((och0*2) ^ swz);
  const int soff0 = (tid>>5)*256 + (((tid&31)*8) ^ (((tid>>5)&7)<<4));

  const int node0 = blockIdx.x * NPB;

  // one-node-ahead prefetch registers
  float4 e0, e1, e2;
  int pidx0, pidx1, pidx2; float pmk0, pmk1, pmk2;
  {
    const float4* ef = (const float4*)(hE + (size_t)node0 * 6144);
    e0 = ef[tid]; e1 = ef[tid + 512]; e2 = ef[tid + 1024];
    const int* ip = Eidx + node0*48 + l15;
    pidx0 = ip[0]; pidx1 = ip[16]; pidx2 = ip[32];
    const float* mp = maskA + node0*48 + l15;
    pmk0 = mp[0]; pmk1 = mp[16]; pmk2 = mp[32];
  }

#pragma unroll 1
  for (int i = 0; i < NPB; ++i){
    const int node = node0 + i;
    const size_t bb = ((size_t)(node >> 11)) << 11;
    char* sEc = sE[i & 1];

    // consume prefetched idx/mask; issue hVp gathers (bf16, consumed after GEMM1)
    const float mk0 = pmk0, mk1 = pmk1, mk2 = pmk2;
    uint2 hp0, hp1, hp2;
    {
      const unsigned short* base = hVpb + bb*128 + och0;
      hp0 = *(const uint2*)(base + (size_t)pidx0 * 128);
      hp1 = *(const uint2*)(base + (size_t)pidx1 * 128);
      hp2 = *(const uint2*)(base + (size_t)pidx2 * 128);
    }
    // S1: stage h_E tile from prefetched regs
    {
      uint2 p;
      p.x = pack2(e0.x, e0.y); p.y = pack2(e0.z, e0.w);
      *(uint2*)(sEc + soff0) = p;
      p.x = pack2(e1.x, e1.y); p.y = pack2(e1.z, e1.w);
      *(uint2*)(sEc + soff0 + 4096) = p;
      p.x = pack2(e2.x, e2.y); p.y = pack2(e2.z, e2.w);
      *(uint2*)(sEc + soff0 + 8192) = p;
    }
    // prefetch next node
    if (i + 1 < NPB){
      const float4* ef = (const float4*)(hE + (size_t)(node + 1) * 6144);
      e0 = ef[tid]; e1 = ef[tid + 512]; e2 = ef[tid + 1024];
      const int* ip = Eidx + (node+1)*48 + l15;
      pidx0 = ip[0]; pidx1 = ip[16]; pidx2 = ip[32];
      const float* mp = maskA + (node+1)*48 + l15;
      pmk0 = mp[0]; pmk1 = mp[16]; pmk2 = mp[32];
    }
    __syncthreads();                                   // B1: sEc staged

    // ---- GEMM1: K=128 (h_E x W1e)
    f32x4 a0 = f32x4{0.f,0.f,0.f,0.f}, a1 = a0, a2 = a0;
#pragma unroll
    for (int ks = 0; ks < 4; ++ks){
      bf16x8 x0 = *(const bf16x8*)(sEc + xoff[ks]);
      bf16x8 x1 = *(const bf16x8*)(sEc + xoff[ks] + 4096);
      bf16x8 x2 = *(const bf16x8*)(sEc + xoff[ks] + 8192);
      a0 = MFMA16(w1f[ks], x0, a0);
      a1 = MFMA16(w1f[ks], x1, a1);
      a2 = MFMA16(w1f[ks], x2, a2);
    }
    // E1: + gathered hVp (has b1), gelu -> sM
    {
      uint2 p;
      p.x = pack2(gelu_fast_f(a0[0] + bflo(hp0.x)), gelu_fast_f(a0[1] + bfhi(hp0.x)));
      p.y = pack2(gelu_fast_f(a0[2] + bflo(hp0.y)), gelu_fast_f(a0[3] + bfhi(hp0.y)));
      *(uint2*)(sM + woff) = p;
      p.x = pack2(gelu_fast_f(a1[0] + bflo(hp1.x)), gelu_fast_f(a1[1] + bfhi(hp1.x)));
      p.y = pack2(gelu_fast_f(a1[2] + bflo(hp1.y)), gelu_fast_f(a1[3] + bfhi(hp1.y)));
      *(uint2*)(sM + woff + 4096) = p;
      p.x = pack2(gelu_fast_f(a2[0] + bflo(hp2.x)), gelu_fast_f(a2[1] + bfhi(hp2.x)));
      p.y = pack2(gelu_fast_f(a2[2] + bflo(hp2.y)), gelu_fast_f(a2[3] + bfhi(hp2.y)));
      *(uint2*)(sM + woff + 8192) = p;
    }
    __syncthreads();                                   // B2: sM ready

    // ---- GEMM2: K=128
    a0 = f32x4{0.f,0.f,0.f,0.f}; a1 = a0; a2 = a0;
#pragma unroll
    for (int ks = 0; ks < 4; ++ks){
      bf16x8 x0 = *(const bf16x8*)(sM + xoff[ks]);
      bf16x8 x1 = *(const bf16x8*)(sM + xoff[ks] + 4096);
      bf16x8 x2 = *(const bf16x8*)(sM + xoff[ks] + 8192);
      a0 = MFMA16(w2f[ks], x0, a0);
      a1 = MFMA16(w2f[ks], x1, a1);
      a2 = MFMA16(w2f[ks], x2, a2);
    }
    // E2: m2 = gelu(acc + b2); masked sum over 48 edges -> S[node][ch]/30
    {
      float s0, s1, s2, s3;
      s0  = mk0 * gelu_fast_f(a0[0] + b2q.x);
      s1  = mk0 * gelu_fast_f(a0[1] + b2q.y);
      s2  = mk0 * gelu_fast_f(a0[2] + b2q.z);
      s3  = mk0 * gelu_fast_f(a0[3] + b2q.w);
      s0 += mk1 * gelu_fast_f(a1[0] + b2q.x);
      s1 += mk1 * gelu_fast_f(a1[1] + b2q.y);
      s2 += mk1 * gelu_fast_f(a1[2] + b2q.z);
      s3 += mk1 * gelu_fast_f(a1[3] + b2q.w);
      s0 += mk2 * gelu_fast_f(a2[0] + b2q.x);
      s1 += mk2 * gelu_fast_f(a2[1] + b2q.y);
      s2 += mk2 * gelu_fast_f(a2[2] + b2q.z);
      s3 += mk2 * gelu_fast_f(a2[3] + b2q.w);
#pragma unroll
      for (int off = 1; off < 16; off <<= 1){
        s0 += __shfl_xor(s0, off);     // width-64: identical result for xor<16,
        s1 += __shfl_xor(s1, off);     // avoids width-16 lane-mask arithmetic
        s2 += __shfl_xor(s2, off);
        s3 += __shfl_xor(s3, off);
      }
      if (l15 == 0){
        float4 o;
        o.x = s0 * (1.0f/30.0f);
        o.y = s1 * (1.0f/30.0f);
        o.z = s2 * (1.0f/30.0f);
        o.w = s3 * (1.0f/30.0f);
        *(float4*)(S + (size_t)node*128 + och0) = o;
      }
      if (wv == 0){
        float q = mk0 + mk1 + mk2;
#pragma unroll
        for (int off = 1; off < 16; off <<= 1) q += __shfl_xor(q, off);
        if (ln == 0) msums[node] = q * (1.0f/30.0f);
      }
    }
  }
}

// ---------------- FFN (+ commuted W3 matvec front) ----------------
__global__ __launch_bounds__(256, 2)
void k_ffn(const float* __restrict__ hV, const float* __restrict__ S,
           const float* __restrict__ msums, const float* __restrict__ maskV,
           const unsigned short* __restrict__ wt,
           const float* __restrict__ b3, const float* __restrict__ bin,
           const float* __restrict__ bout, float* __restrict__ out)
{
  __shared__ char  sS[32*256];    // 32 nodes x 128 bf16 (swizzled) : S
  __shared__ char  sH[32*256];    // 32 nodes x 128 bf16 (swizzled) : h
  __shared__ float sHf[32*132];   // fp32 h (padded rows, for residual)
  __shared__ char  sF[32*1024];   // 32 nodes x 512 bf16 (swizzled) : ff

  const int tid = threadIdx.x;
  const int wv  = tid >> 6;
  const int ln  = tid & 63;
  const int l15 = ln & 15;
  const int l4  = ln >> 4;
  const int swz = (l15 & 7) << 4;
  const unsigned short* W3T   = wt + 49152;    // [128][128]
  const unsigned short* WinT  = wt + 65536;    // [512][128]
  const unsigned short* WoutT = wt + 131072;   // [128][512]
  const int nb = blockIdx.x * 32;              // flat node base

  // stage S tile
#pragma unroll
  for (int it = 0; it < 2; ++it){
    int cid = tid + it*256;          // 32 rows x 16 chunks
    int r = cid >> 4, cb = cid & 15;
    const float* src = S + (size_t)(nb + r)*128 + cb*8;
    float4 a0 = *(const float4*)(src);
    float4 a1 = *(const float4*)(src + 4);
    uint4 w;
    w.x = pack2(a0.x, a0.y); w.y = pack2(a0.z, a0.w);
    w.z = pack2(a1.x, a1.y); w.w = pack2(a1.z, a1.w);
    *(uint4*)(&sS[r*256 + ((cb*16) ^ ((r&7)<<4))]) = w;
  }
  __syncthreads();

  // G0: dh^T[128][32] = W3T x S^T, K=128 ; h = hV + dh + msum*b3
  {
    f32x4 acc[2][2];
#pragma unroll
    for (int m = 0; m < 2; ++m){ acc[m][0] = f32x4{0.f,0.f,0.f,0.f}; acc[m][1] = f32x4{0.f,0.f,0.f,0.f}; }
#pragma unroll
    for (int ks = 0; ks < 4; ++ks){
      bf16x8 x0 = *(const bf16x8*)(&sS[(l15)*256      + ((ks*64 + l4*16) ^ swz)]);
      bf16x8 x1 = *(const bf16x8*)(&sS[(16 + l15)*256 + ((ks*64 + l4*16) ^ swz)]);
#pragma unroll
      for (int m = 0; m < 2; ++m){
        int cr = (wv*2 + m)*16 + l15;
        bf16x8 wf = *(const bf16x8*)(W3T + cr*128 + ks*32 + l4*8);
        acc[m][0] = MFMA16(wf, x0, acc[m][0]);
        acc[m][1] = MFMA16(wf, x1, acc[m][1]);
      }
    }
#pragma unroll
    for (int m = 0; m < 2; ++m){
      int ch0 = (wv*2 + m)*16 + l4*4;
      const float4 b3q = *(const float4*)(b3 + ch0);
#pragma unroll
      for (int nt = 0; nt < 2; ++nt){
        int row  = nt*16 + l15;
        int node = nb + row;
        float ms = msums[node];
        const float4 hv = *(const float4*)(hV + (size_t)node*128 + ch0);
        float h0 = hv.x + acc[m][nt][0] + ms*b3q.x;
        float h1 = hv.y + acc[m][nt][1] + ms*b3q.y;
        float h2 = hv.z + acc[m][nt][2] + ms*b3q.z;
        float h3 = hv.w + acc[m][nt][3] + ms*b3q.w;
        float4 hf; hf.x = h0; hf.y = h1; hf.z = h2; hf.w = h3;
        *(float4*)(&sHf[row*132 + ch0]) = hf;
        uint2 p; p.x = pack2(h0, h1); p.y = pack2(h2, h3);
        *(uint2*)(&sH[row*256 + ((ch0*2) ^ ((row&7)<<4))]) = p;
      }
    }
  }
  __syncthreads();

  // G1: ff^T[512][32] = WinT x h^T, K=128 — wave owns 8 f-tiles
  f32x4 accA[8][2];
#pragma unroll
  for (int m8 = 0; m8 < 8; ++m8){ accA[m8][0] = f32x4{0.f,0.f,0.f,0.f}; accA[m8][1] = f32x4{0.f,0.f,0.f,0.f}; }
#pragma unroll
  for (int ks = 0; ks < 4; ++ks){
    bf16x8 x0 = *(const bf16x8*)(&sH[(l15)*256      + ((ks*64 + l4*16) ^ swz)]);
    bf16x8 x1 = *(const bf16x8*)(&sH[(16 + l15)*256 + ((ks*64 + l4*16) ^ swz)]);
#pragma unroll
    for (int m8 = 0; m8 < 8; ++m8){
      int fr = (wv*8 + m8)*16 + l15;
      bf16x8 wf = *(const bf16x8*)(WinT + fr*128 + ks*32 + l4*8);
      accA[m8][0] = MFMA16(wf, x0, accA[m8][0]);
      accA[m8][1] = MFMA16(wf, x1, accA[m8][1]);
    }
  }
#pragma unroll
  for (int m8 = 0; m8 < 8; ++m8){
    int f0 = (wv*8 + m8)*16 + l4*4;
    float q0 = bin[f0], q1 = bin[f0+1], q2 = bin[f0+2], q3 = bin[f0+3];
#pragma unroll
    for (int nt = 0; nt < 2; ++nt){
      int row = nt*16 + l15;
      float g0 = gelu_erf_f(accA[m8][nt][0] + q0);
      float g1 = gelu_erf_f(accA[m8][nt][1] + q1);
      float g2 = gelu_erf_f(accA[m8][nt][2] + q2);
      float g3 = gelu_erf_f(accA[m8][nt][3] + q3);
      uint2 p; p.x = pack2(g0, g1); p.y = pack2(g2, g3);
      *(uint2*)(&sF[row*1024 + ((f0*2) ^ swz)]) = p;
    }
  }
  __syncthreads();

  // G2: dh2^T[128][32] = WoutT x ff^T, K=512 — wave owns 2 ch-tiles
  f32x4 accB[2][2];
#pragma unroll
  for (int m = 0; m < 2; ++m){ accB[m][0] = f32x4{0.f,0.f,0.f,0.f}; accB[m][1] = f32x4{0.f,0.f,0.f,0.f}; }
#pragma unroll
  for (int ks = 0; ks < 16; ++ks){
    bf16x8 x0 = *(const bf16x8*)(&sF[(l15)*1024      + ((ks*64 + l4*16) ^ swz)]);
    bf16x8 x1 = *(const bf16x8*)(&sF[(16 + l15)*1024 + ((ks*64 + l4*16) ^ swz)]);
#pragma unroll
    for (int m = 0; m < 2; ++m){
      int cr = (wv*2 + m)*16 + l15;
      bf16x8 wf = *(const bf16x8*)(WoutT + cr*512 + ks*32 + l4*8);
      accB[m][0] = MFMA16(wf, x0, accB[m][0]);
      accB[m][1] = MFMA16(wf, x1, accB[m][1]);
    }
  }
#pragma unroll
  for (int m = 0; m < 2; ++m){
    int ch0 = (wv*2 + m)*16 + l4*4;
    float q0 = bout[ch0], q1 = bout[ch0+1], q2 = bout[ch0+2], q3 = bout[ch0+3];
#pragma unroll
    for (int nt = 0; nt < 2; ++nt){
      int row  = nt*16 + l15;
      int node = nb + row;
      float mv = maskV[node];
      const float4 hf = *(const float4*)(&sHf[row*132 + ch0]);
      float4 o;
      o.x = mv * (hf.x + accB[m][nt][0] + q0);
      o.y = mv * (hf.y + accB[m][nt][1] + q1);
      o.z = mv * (hf.z + accB[m][nt][2] + q2);
      o.w = mv * (hf.w + accB[m][nt][3] + q3);
      *(float4*)(out + (size_t)node*128 + ch0) = o;
    }
  }
}

extern "C" void kernel_launch(void* const* d_in, const int* in_sizes, int n_in,
                              void* d_out, int out_size, void* d_ws, size_t ws_size,
                              hipStream_t stream)
{
  const float* hV    = (const float*)d_in[0];
  const float* hE    = (const float*)d_in[1];
  const int*   Eidx  = (const int*)  d_in[2];
  const float* maskV = (const float*)d_in[3];
  const float* maskA = (const float*)d_in[4];
  const float* W1w = (const float*)d_in[5];
  const float* W1b = (const float*)d_in[6];
  const float* W2w = (const float*)d_in[7];
  const float* W2b = (const float*)d_in[8];
  const float* W3w = (const float*)d_in[9];
  const float* W3b = (const float*)d_in[10];
  const float* Winw  = (const float*)d_in[11];
  const float* Winb  = (const float*)d_in[12];
  const float* Woutw = (const float*)d_in[13];
  const float* Woutb = (const float*)d_in[14];
  float* out = (float*)d_out;

  unsigned short* wt   = (unsigned short*)d_ws;                        // 384 KB bf16 weights
  unsigned short* hVpb = (unsigned short*)((char*)d_ws + (1u << 19));  // 2 MB bf16 hVp
  float* Sbuf  = (float*)((char*)d_ws + (1u << 19) + (1u << 21));      // 4 MB fp32 S
  float* msums = (float*)((char*)d_ws + (1u << 19) + (1u << 21) + (1u << 22)); // 32 KB

  k_prep<<<dim3(768),  dim3(256), 0, stream>>>(W1w, W2w, W3w, Winw, Woutw, wt);
  k_hvp <<<dim3(256),  dim3(256), 0, stream>>>(hV, wt, W1b, hVpb);
  k_msg <<<dim3(2048), dim3(512), 0, stream>>>(hE, Eidx, maskA, wt, hVpb, W2b, Sbuf, msums);
  k_ffn <<<dim3(256),  dim3(256), 0, stream>>>(hV, Sbuf, msums, maskV, wt, W3b, Winb, Woutb, out);
}